// Round 1
// baseline (866.186 us; speedup 1.0000x reference)
//
#include <hip/hip_runtime.h>
#include <hip/hip_bf16.h>

#define N_ENT   50000
#define N_EDGE  600000
#define FEAT    128
#define HID     256
#define OUT_D   128
#define NB      16
#define BN_EPS  1e-5f

// ---------------- ws layout (bytes) ----------------
// agg    [N_ENT][FEAT] f32 @ 0                (25,600,000)
// deg    [N_ENT]       f32 @ 25,600,000       (200,000)
// colsum [HID]         f32 @ 25,800,000       (1,024)
// colsq  [HID]         f32 @ 25,801,024       (1,024)
// scale  [HID]         f32 @ 25,802,048       (1,024)
// shift  [HID]         f32 @ 25,803,072       (1,024)
// y      [N_ENT][HID]  f32 @ 25,804,096       (51,200,000)
// total: 77,004,096

#define FMA4(ACC, S, W) do { (ACC).x += (S) * (W).x; (ACC).y += (S) * (W).y; \
                             (ACC).z += (S) * (W).z; (ACC).w += (S) * (W).w; } while (0)

// ---- Kernel 1: edge scatter (msg = x[src] + rel[et], agg[dst] += msg, deg[dst] += 1)
__global__ __launch_bounds__(256) void k_scatter(
    const int* __restrict__ ei, const int* __restrict__ et,
    const float* __restrict__ x, const float* __restrict__ rel,
    float* __restrict__ agg, float* __restrict__ deg)
{
    int e    = blockIdx.x * 4 + (threadIdx.x >> 6);   // one edge per wave
    int lane = threadIdx.x & 63;
    int src = ei[e];
    int dst = ei[N_EDGE + e];
    int t   = et[e];
    float2 xv = ((const float2*)(x   + src * FEAT))[lane];
    float2 rv = ((const float2*)(rel + t   * FEAT))[lane];
    float* ap = agg + dst * FEAT + lane * 2;
    atomicAdd(ap,     xv.x + rv.x);
    atomicAdd(ap + 1, xv.y + rv.y);
    if (lane == 0) atomicAdd(deg + dst, 1.0f);
}

// ---- Kernel 2: h = (agg/deg)@W_msg + x@W_self + b_msg ; y = h@W1 + b1 ; col stats
__global__ __launch_bounds__(256) void k_hy(
    const float* __restrict__ agg, const float* __restrict__ deg,
    const float* __restrict__ x,
    const float* __restrict__ Wm,  const float* __restrict__ bm,
    const float* __restrict__ Wsf, const float* __restrict__ W1,
    const float* __restrict__ b1,
    float* __restrict__ y, float* __restrict__ colsum, float* __restrict__ colsq)
{
    __shared__ float a_s[NB][FEAT];
    __shared__ float x_s[NB][FEAT];
    __shared__ float h_s[NB][HID];
    __shared__ float red_s[2][4][HID];

    int tid = threadIdx.x;
    int n0  = blockIdx.x * NB;

    // load + degree-normalize 16 rows of agg and x (float4-coalesced)
    #pragma unroll
    for (int i = 0; i < 2; ++i) {
        int f    = tid + i * 256;          // float4 index in 16x128
        int flat = f * 4;
        int row  = flat >> 7;
        int col  = flat & (FEAT - 1);
        int node = n0 + row;
        float invd = 1.0f / fmaxf(deg[node], 1.0f);
        float4 av = *(const float4*)(agg + node * FEAT + col);
        float4 xv = *(const float4*)(x   + node * FEAT + col);
        av.x *= invd; av.y *= invd; av.z *= invd; av.w *= invd;
        *(float4*)&a_s[row][col] = av;
        *(float4*)&x_s[row][col] = xv;
    }
    __syncthreads();

    int w    = tid >> 6;        // wave id: nodes 4w..4w+3
    int lane = tid & 63;        // lane: cols 4*lane..4*lane+3
    int c0   = lane * 4;
    int nb   = w * 4;

    // ---- h phase (K = 128, two weight matrices)
    float4 acc[4];
    {
        float4 bmv = *(const float4*)(bm + c0);
        #pragma unroll
        for (int n = 0; n < 4; ++n) acc[n] = bmv;
    }
    for (int k = 0; k < FEAT; k += 4) {
        float4 wm[4], wsf[4];
        #pragma unroll
        for (int kk = 0; kk < 4; ++kk) {
            wm[kk]  = *(const float4*)(Wm  + (k + kk) * HID + c0);
            wsf[kk] = *(const float4*)(Wsf + (k + kk) * HID + c0);
        }
        float4 av[4], xv[4];
        #pragma unroll
        for (int n = 0; n < 4; ++n) {
            av[n] = *(const float4*)&a_s[nb + n][k];
            xv[n] = *(const float4*)&x_s[nb + n][k];
        }
        #pragma unroll
        for (int n = 0; n < 4; ++n) {
            #pragma unroll
            for (int kk = 0; kk < 4; ++kk) {
                float a  = ((const float*)&av[n])[kk];
                float xx = ((const float*)&xv[n])[kk];
                FMA4(acc[n], a,  wm[kk]);
                FMA4(acc[n], xx, wsf[kk]);
            }
        }
    }
    #pragma unroll
    for (int n = 0; n < 4; ++n)
        *(float4*)&h_s[nb + n][c0] = acc[n];
    __syncthreads();

    // ---- y phase (K = 256)
    float4 acc2[4];
    {
        float4 b1v = *(const float4*)(b1 + c0);
        #pragma unroll
        for (int n = 0; n < 4; ++n) acc2[n] = b1v;
    }
    for (int k = 0; k < HID; k += 4) {
        float4 w1v[4];
        #pragma unroll
        for (int kk = 0; kk < 4; ++kk)
            w1v[kk] = *(const float4*)(W1 + (k + kk) * HID + c0);
        float4 hv[4];
        #pragma unroll
        for (int n = 0; n < 4; ++n)
            hv[n] = *(const float4*)&h_s[nb + n][k];
        #pragma unroll
        for (int n = 0; n < 4; ++n) {
            #pragma unroll
            for (int kk = 0; kk < 4; ++kk) {
                float h = ((const float*)&hv[n])[kk];
                FMA4(acc2[n], h, w1v[kk]);
            }
        }
    }

    // write y + per-block column partial sums
    float4 s = make_float4(0.f, 0.f, 0.f, 0.f);
    float4 q = make_float4(0.f, 0.f, 0.f, 0.f);
    #pragma unroll
    for (int n = 0; n < 4; ++n) {
        float4 v = acc2[n];
        *(float4*)(y + (n0 + nb + n) * HID + c0) = v;
        s.x += v.x; s.y += v.y; s.z += v.z; s.w += v.w;
        q.x += v.x * v.x; q.y += v.y * v.y; q.z += v.z * v.z; q.w += v.w * v.w;
    }
    *(float4*)&red_s[0][w][c0] = s;
    *(float4*)&red_s[1][w][c0] = q;
    __syncthreads();
    {
        int c = tid;
        float ssum = red_s[0][0][c] + red_s[0][1][c] + red_s[0][2][c] + red_s[0][3][c];
        float qsum = red_s[1][0][c] + red_s[1][1][c] + red_s[1][2][c] + red_s[1][3][c];
        atomicAdd(colsum + c, ssum);
        atomicAdd(colsq  + c, qsum);
    }
}

// ---- Kernel 3: finalize BN stats -> scale/shift
__global__ __launch_bounds__(256) void k_stats(
    const float* __restrict__ colsum, const float* __restrict__ colsq,
    const float* __restrict__ gamma,  const float* __restrict__ beta,
    float* __restrict__ scale, float* __restrict__ shift)
{
    int c = threadIdx.x;
    const float invn = 1.0f / (float)N_ENT;
    float mean = colsum[c] * invn;
    float var  = colsq[c] * invn - mean * mean;
    float rstd = rsqrtf(var + BN_EPS);
    float sc   = gamma[c] * rstd;
    scale[c] = sc;
    shift[c] = beta[c] - mean * sc;
}

// ---- Kernel 4: out = relu(y*scale + shift) @ W2 + b2
__global__ __launch_bounds__(256) void k_out(
    const float* __restrict__ y, const float* __restrict__ scale,
    const float* __restrict__ shift, const float* __restrict__ W2,
    const float* __restrict__ b2, float* __restrict__ out)
{
    __shared__ float z_s[NB][HID];
    int tid = threadIdx.x;
    int n0  = blockIdx.x * NB;

    #pragma unroll
    for (int i = 0; i < 4; ++i) {
        int f    = tid + i * 256;          // float4 index in 16x256
        int flat = f * 4;
        int row  = flat >> 8;
        int col  = flat & (HID - 1);
        float4 v  = *(const float4*)(y + (n0 + row) * HID + col);
        float4 sc = *(const float4*)(scale + col);
        float4 sh = *(const float4*)(shift + col);
        v.x = fmaxf(v.x * sc.x + sh.x, 0.f);
        v.y = fmaxf(v.y * sc.y + sh.y, 0.f);
        v.z = fmaxf(v.z * sc.z + sh.z, 0.f);
        v.w = fmaxf(v.w * sc.w + sh.w, 0.f);
        *(float4*)&z_s[row][col] = v;
    }
    __syncthreads();

    int cg = tid & 31, ng = tid >> 5;      // 32 col-groups x 8 node-groups
    int c0 = cg * 4;
    int nb = ng * 2;

    float4 acc[2];
    {
        float4 b2v = *(const float4*)(b2 + c0);
        acc[0] = b2v; acc[1] = b2v;
    }
    for (int k = 0; k < HID; k += 4) {
        float4 w2v[4];
        #pragma unroll
        for (int kk = 0; kk < 4; ++kk)
            w2v[kk] = *(const float4*)(W2 + (k + kk) * OUT_D + c0);
        float4 zv[2];
        #pragma unroll
        for (int n = 0; n < 2; ++n)
            zv[n] = *(const float4*)&z_s[nb + n][k];
        #pragma unroll
        for (int n = 0; n < 2; ++n) {
            #pragma unroll
            for (int kk = 0; kk < 4; ++kk) {
                float z = ((const float*)&zv[n])[kk];
                FMA4(acc[n], z, w2v[kk]);
            }
        }
    }
    #pragma unroll
    for (int n = 0; n < 2; ++n)
        *(float4*)(out + (n0 + nb + n) * OUT_D + c0) = acc[n];
}

extern "C" void kernel_launch(void* const* d_in, const int* in_sizes, int n_in,
                              void* d_out, int out_size, void* d_ws, size_t ws_size,
                              hipStream_t stream)
{
    const int*   ei    = (const int*)d_in[0];
    const int*   et    = (const int*)d_in[1];
    const float* x     = (const float*)d_in[2];
    const float* rel   = (const float*)d_in[3];
    const float* Wm    = (const float*)d_in[4];
    const float* bm    = (const float*)d_in[5];
    const float* Wsf   = (const float*)d_in[6];
    const float* W1    = (const float*)d_in[7];
    const float* b1    = (const float*)d_in[8];
    const float* gamma = (const float*)d_in[9];
    const float* beta  = (const float*)d_in[10];
    const float* W2    = (const float*)d_in[11];
    const float* b2    = (const float*)d_in[12];
    float* out = (float*)d_out;

    char* ws = (char*)d_ws;
    float* agg    = (float*)(ws + 0);
    float* deg    = (float*)(ws + 25600000);
    float* colsum = (float*)(ws + 25800000);
    float* colsq  = (float*)(ws + 25801024);
    float* scale  = (float*)(ws + 25802048);
    float* shift  = (float*)(ws + 25803072);
    float* y      = (float*)(ws + 25804096);

    // zero agg + deg + colsum + colsq (25,802,048 bytes)
    hipMemsetAsync(d_ws, 0, 25802048, stream);

    k_scatter<<<N_EDGE / 4, 256, 0, stream>>>(ei, et, x, rel, agg, deg);
    k_hy<<<N_ENT / NB, 256, 0, stream>>>(agg, deg, x, Wm, bm, Wsf, W1, b1, y, colsum, colsq);
    k_stats<<<1, 256, 0, stream>>>(colsum, colsq, gamma, beta, scale, shift);
    k_out<<<N_ENT / NB, 256, 0, stream>>>(y, scale, shift, W2, b2, out);
}

// Round 2
// 597.258 us; speedup vs baseline: 1.4503x; 1.4503x over previous
//
#include <hip/hip_runtime.h>
#include <hip/hip_bf16.h>

#define N_ENT   50000
#define N_EDGE  600000
#define FEAT    128
#define HID     256
#define OUT_D   128
#define NB      16
#define BN_EPS  1e-5f

// ---------------- ws layout (bytes) ----------------
// degi   [N_ENT]  i32 @ 0            (200,000)
// colsum [HID]    f32 @ 200,000      (1,024)
// colsq  [HID]    f32 @ 201,024      (1,024)
// scale  [HID]    f32 @ 202,048      (1,024)
// shift  [HID]    f32 @ 203,072      (1,024)
// agg    [N_ENT][FEAT] f32 @ 204,096 (25,600,000)
// y      [N_ENT][HID]  f32 @ 25,804,096 (51,200,000)  -- total 77,004,096
//   CSR arrays overlay head of y (consumed before y is written):
//   rowptr [N_ENT+1] i32 @ y+0        (200,064 padded)
//   fillc  [N_ENT]   i32 @ y+200,064  (200,000)
//   packed [N_EDGE]  i32 @ y+400,064  (2,400,000)

#define FMA4(ACC, S, W) do { (ACC).x += (S) * (W).x; (ACC).y += (S) * (W).y; \
                             (ACC).z += (S) * (W).z; (ACC).w += (S) * (W).w; } while (0)

// ---- Kernel 1a: degree histogram
__global__ __launch_bounds__(256) void k_deg(
    const int* __restrict__ ei, int* __restrict__ degi)
{
    int e = blockIdx.x * 256 + threadIdx.x;
    if (e < N_EDGE) atomicAdd(&degi[ei[N_EDGE + e]], 1);
}

// ---- Kernel 1b: exclusive scan (single block) -> rowptr, fillc
__global__ __launch_bounds__(256) void k_scan(
    const int* __restrict__ degi, int* __restrict__ rowptr, int* __restrict__ fillc)
{
    __shared__ int part[256];
    int t = threadIdx.x;
    const int CH = (N_ENT + 255) / 256;        // 196
    int lo = t * CH, hi = min(lo + CH, N_ENT);
    int s = 0;
    for (int i = lo; i < hi; ++i) s += degi[i];
    part[t] = s;
    __syncthreads();
    for (int off = 1; off < 256; off <<= 1) {  // inclusive scan of partials
        int v = (t >= off) ? part[t - off] : 0;
        __syncthreads();
        part[t] += v;
        __syncthreads();
    }
    int run = (t == 0) ? 0 : part[t - 1];
    for (int i = lo; i < hi; ++i) {
        rowptr[i] = run;
        fillc[i]  = run;
        run += degi[i];
    }
    if (t == 255) rowptr[N_ENT] = run;
}

// ---- Kernel 1c: bucket-fill packed (src | type<<16) into dst segments
__global__ __launch_bounds__(256) void k_fill(
    const int* __restrict__ ei, const int* __restrict__ et,
    int* __restrict__ fillc, int* __restrict__ packed)
{
    int e = blockIdx.x * 256 + threadIdx.x;
    if (e >= N_EDGE) return;
    int dst = ei[N_EDGE + e];
    int pos = atomicAdd(&fillc[dst], 1);
    packed[pos] = ei[e] | (et[e] << 16);
}

// ---- Kernel 1d: segment-reduce, one wave per node; writes normalized agg
__global__ __launch_bounds__(256) void k_agg(
    const int* __restrict__ rowptr, const int* __restrict__ packed,
    const float* __restrict__ x, const float* __restrict__ rel,
    float* __restrict__ agg)
{
    int node = blockIdx.x * 4 + (threadIdx.x >> 6);
    int lane = threadIdx.x & 63;
    int e0 = rowptr[node], e1 = rowptr[node + 1];
    float2 acc = make_float2(0.f, 0.f);
    for (int e = e0; e < e1; ++e) {
        int p   = packed[e];
        int src = p & 0xFFFF;
        int typ = p >> 16;
        float2 xv = ((const float2*)(x   + src * FEAT))[lane];
        float2 rv = ((const float2*)(rel + typ * FEAT))[lane];
        acc.x += xv.x + rv.x;
        acc.y += xv.y + rv.y;
    }
    float invd = 1.0f / fmaxf((float)(e1 - e0), 1.0f);
    acc.x *= invd; acc.y *= invd;
    ((float2*)(agg + node * FEAT))[lane] = acc;
}

// ---- Kernel 2: h = agg@W_msg + x@W_self + b_msg ; y = h@W1 + b1 ; col stats
__global__ __launch_bounds__(256) void k_hy(
    const float* __restrict__ agg, const float* __restrict__ x,
    const float* __restrict__ Wm,  const float* __restrict__ bm,
    const float* __restrict__ Wsf, const float* __restrict__ W1,
    const float* __restrict__ b1,
    float* __restrict__ y, float* __restrict__ colsum, float* __restrict__ colsq)
{
    __shared__ float a_s[NB][FEAT];
    __shared__ float x_s[NB][FEAT];
    __shared__ float h_s[NB][HID];
    __shared__ float red_s[2][4][HID];

    int tid = threadIdx.x;
    int n0  = blockIdx.x * NB;

    #pragma unroll
    for (int i = 0; i < 2; ++i) {
        int f    = tid + i * 256;          // float4 index in 16x128
        int flat = f * 4;
        int row  = flat >> 7;
        int col  = flat & (FEAT - 1);
        int node = n0 + row;
        float4 av = *(const float4*)(agg + node * FEAT + col);
        float4 xv = *(const float4*)(x   + node * FEAT + col);
        *(float4*)&a_s[row][col] = av;
        *(float4*)&x_s[row][col] = xv;
    }
    __syncthreads();

    int w    = tid >> 6;        // wave id: nodes 4w..4w+3
    int lane = tid & 63;        // lane: cols 4*lane..4*lane+3
    int c0   = lane * 4;
    int nb   = w * 4;

    // ---- h phase (K = 128, two weight matrices)
    float4 acc[4];
    {
        float4 bmv = *(const float4*)(bm + c0);
        #pragma unroll
        for (int n = 0; n < 4; ++n) acc[n] = bmv;
    }
    for (int k = 0; k < FEAT; k += 4) {
        float4 wm[4], wsf[4];
        #pragma unroll
        for (int kk = 0; kk < 4; ++kk) {
            wm[kk]  = *(const float4*)(Wm  + (k + kk) * HID + c0);
            wsf[kk] = *(const float4*)(Wsf + (k + kk) * HID + c0);
        }
        float4 av[4], xv[4];
        #pragma unroll
        for (int n = 0; n < 4; ++n) {
            av[n] = *(const float4*)&a_s[nb + n][k];
            xv[n] = *(const float4*)&x_s[nb + n][k];
        }
        #pragma unroll
        for (int n = 0; n < 4; ++n) {
            #pragma unroll
            for (int kk = 0; kk < 4; ++kk) {
                float a  = ((const float*)&av[n])[kk];
                float xx = ((const float*)&xv[n])[kk];
                FMA4(acc[n], a,  wm[kk]);
                FMA4(acc[n], xx, wsf[kk]);
            }
        }
    }
    #pragma unroll
    for (int n = 0; n < 4; ++n)
        *(float4*)&h_s[nb + n][c0] = acc[n];
    __syncthreads();

    // ---- y phase (K = 256)
    float4 acc2[4];
    {
        float4 b1v = *(const float4*)(b1 + c0);
        #pragma unroll
        for (int n = 0; n < 4; ++n) acc2[n] = b1v;
    }
    for (int k = 0; k < HID; k += 4) {
        float4 w1v[4];
        #pragma unroll
        for (int kk = 0; kk < 4; ++kk)
            w1v[kk] = *(const float4*)(W1 + (k + kk) * HID + c0);
        float4 hv[4];
        #pragma unroll
        for (int n = 0; n < 4; ++n)
            hv[n] = *(const float4*)&h_s[nb + n][k];
        #pragma unroll
        for (int n = 0; n < 4; ++n) {
            #pragma unroll
            for (int kk = 0; kk < 4; ++kk) {
                float h = ((const float*)&hv[n])[kk];
                FMA4(acc2[n], h, w1v[kk]);
            }
        }
    }

    float4 s = make_float4(0.f, 0.f, 0.f, 0.f);
    float4 q = make_float4(0.f, 0.f, 0.f, 0.f);
    #pragma unroll
    for (int n = 0; n < 4; ++n) {
        float4 v = acc2[n];
        *(float4*)(y + (n0 + nb + n) * HID + c0) = v;
        s.x += v.x; s.y += v.y; s.z += v.z; s.w += v.w;
        q.x += v.x * v.x; q.y += v.y * v.y; q.z += v.z * v.z; q.w += v.w * v.w;
    }
    *(float4*)&red_s[0][w][c0] = s;
    *(float4*)&red_s[1][w][c0] = q;
    __syncthreads();
    {
        int c = tid;
        float ssum = red_s[0][0][c] + red_s[0][1][c] + red_s[0][2][c] + red_s[0][3][c];
        float qsum = red_s[1][0][c] + red_s[1][1][c] + red_s[1][2][c] + red_s[1][3][c];
        atomicAdd(colsum + c, ssum);
        atomicAdd(colsq  + c, qsum);
    }
}

// ---- Kernel 3: finalize BN stats -> scale/shift
__global__ __launch_bounds__(256) void k_stats(
    const float* __restrict__ colsum, const float* __restrict__ colsq,
    const float* __restrict__ gamma,  const float* __restrict__ beta,
    float* __restrict__ scale, float* __restrict__ shift)
{
    int c = threadIdx.x;
    const float invn = 1.0f / (float)N_ENT;
    float mean = colsum[c] * invn;
    float var  = colsq[c] * invn - mean * mean;
    float rstd = rsqrtf(var + BN_EPS);
    float sc   = gamma[c] * rstd;
    scale[c] = sc;
    shift[c] = beta[c] - mean * sc;
}

// ---- Kernel 4: out = relu(y*scale + shift) @ W2 + b2
__global__ __launch_bounds__(256) void k_out(
    const float* __restrict__ y, const float* __restrict__ scale,
    const float* __restrict__ shift, const float* __restrict__ W2,
    const float* __restrict__ b2, float* __restrict__ out)
{
    __shared__ float z_s[NB][HID];
    int tid = threadIdx.x;
    int n0  = blockIdx.x * NB;

    #pragma unroll
    for (int i = 0; i < 4; ++i) {
        int f    = tid + i * 256;          // float4 index in 16x256
        int flat = f * 4;
        int row  = flat >> 8;
        int col  = flat & (HID - 1);
        float4 v  = *(const float4*)(y + (n0 + row) * HID + col);
        float4 sc = *(const float4*)(scale + col);
        float4 sh = *(const float4*)(shift + col);
        v.x = fmaxf(v.x * sc.x + sh.x, 0.f);
        v.y = fmaxf(v.y * sc.y + sh.y, 0.f);
        v.z = fmaxf(v.z * sc.z + sh.z, 0.f);
        v.w = fmaxf(v.w * sc.w + sh.w, 0.f);
        *(float4*)&z_s[row][col] = v;
    }
    __syncthreads();

    int cg = tid & 31, ng = tid >> 5;      // 32 col-groups x 8 node-groups
    int c0 = cg * 4;
    int nb = ng * 2;

    float4 acc[2];
    {
        float4 b2v = *(const float4*)(b2 + c0);
        acc[0] = b2v; acc[1] = b2v;
    }
    for (int k = 0; k < HID; k += 4) {
        float4 w2v[4];
        #pragma unroll
        for (int kk = 0; kk < 4; ++kk)
            w2v[kk] = *(const float4*)(W2 + (k + kk) * OUT_D + c0);
        float4 zv[2];
        #pragma unroll
        for (int n = 0; n < 2; ++n)
            zv[n] = *(const float4*)&z_s[nb + n][k];
        #pragma unroll
        for (int n = 0; n < 2; ++n) {
            #pragma unroll
            for (int kk = 0; kk < 4; ++kk) {
                float z = ((const float*)&zv[n])[kk];
                FMA4(acc[n], z, w2v[kk]);
            }
        }
    }
    #pragma unroll
    for (int n = 0; n < 2; ++n)
        *(float4*)(out + (n0 + nb + n) * OUT_D + c0) = acc[n];
}

extern "C" void kernel_launch(void* const* d_in, const int* in_sizes, int n_in,
                              void* d_out, int out_size, void* d_ws, size_t ws_size,
                              hipStream_t stream)
{
    const int*   ei    = (const int*)d_in[0];
    const int*   et    = (const int*)d_in[1];
    const float* x     = (const float*)d_in[2];
    const float* rel   = (const float*)d_in[3];
    const float* Wm    = (const float*)d_in[4];
    const float* bm    = (const float*)d_in[5];
    const float* Wsf   = (const float*)d_in[6];
    const float* W1    = (const float*)d_in[7];
    const float* b1    = (const float*)d_in[8];
    const float* gamma = (const float*)d_in[9];
    const float* beta  = (const float*)d_in[10];
    const float* W2    = (const float*)d_in[11];
    const float* b2    = (const float*)d_in[12];
    float* out = (float*)d_out;

    char* ws = (char*)d_ws;
    int*   degi   = (int*)(ws + 0);
    float* colsum = (float*)(ws + 200000);
    float* colsq  = (float*)(ws + 201024);
    float* scale  = (float*)(ws + 202048);
    float* shift  = (float*)(ws + 203072);
    float* agg    = (float*)(ws + 204096);
    float* y      = (float*)(ws + 25804096);
    // CSR overlays the head of y (fully consumed before k_hy writes y)
    int*   rowptr = (int*)(ws + 25804096);
    int*   fillc  = (int*)(ws + 25804096 + 200064);
    int*   packed = (int*)(ws + 25804096 + 400064);

    // zero degi + colsum + colsq (contiguous [0, 202048))
    hipMemsetAsync(d_ws, 0, 202048, stream);

    k_deg <<<(N_EDGE + 255) / 256, 256, 0, stream>>>(ei, degi);
    k_scan<<<1, 256, 0, stream>>>(degi, rowptr, fillc);
    k_fill<<<(N_EDGE + 255) / 256, 256, 0, stream>>>(ei, et, fillc, packed);
    k_agg <<<N_ENT / 4, 256, 0, stream>>>(rowptr, packed, x, rel, agg);
    k_hy  <<<N_ENT / NB, 256, 0, stream>>>(agg, x, Wm, bm, Wsf, W1, b1, y, colsum, colsq);
    k_stats<<<1, 256, 0, stream>>>(colsum, colsq, gamma, beta, scale, shift);
    k_out <<<N_ENT / NB, 256, 0, stream>>>(y, scale, shift, W2, b2, out);
}

// Round 3
// 338.086 us; speedup vs baseline: 2.5620x; 1.7666x over previous
//
#include <hip/hip_runtime.h>
#include <hip/hip_bf16.h>

#define N_ENT   50000
#define N_EDGE  600000
#define FEAT    128
#define HID     256
#define OUT_D   128
#define MROWS   50048        // N_ENT padded to 64
#define BN_EPS  1e-5f

// ---------------- ws layout (bytes) ----------------
#define OFF_DEGI    0               // [N_ENT] i32          200,000
#define OFF_COLSUM  200000          // [HID] f32            1,024
#define OFF_COLSQ   201024          // [HID] f32            1,024
#define OFF_SCALE   202048          // [HID] f32            1,024
#define OFF_SHIFT   203072          // [HID] f32            1,024
#define OFF_RELB    204096          // [101][128] bf16      25,856
#define OFF_WT1     229952          // [256][256] bf16 (WmWsf^T stacked)  131,072
#define OFF_W1T     361024          // [256][256] bf16      131,072
#define OFF_W2T     492096          // [128][256] bf16      65,536
#define OFF_A       557632          // [MROWS][256] bf16 ([agg|x])  25,624,576
#define OFF_Y       26182208        // [MROWS][256] bf16 (swizzled granules) 25,624,576
// CSR overlays head of Y region (consumed before k_hy writes y):
#define OFF_ROWPTR  26182208
#define OFF_FILLC   (26182208 + 200064)
#define OFF_PACKED  (26182208 + 400064)

typedef __attribute__((ext_vector_type(8))) short bf16x8;
typedef __attribute__((ext_vector_type(4))) float f32x4;

__device__ __forceinline__ ushort f2bf(float f) {
    uint u = __float_as_uint(f);
    return (ushort)((u + 0x7FFFu + ((u >> 16) & 1u)) >> 16);
}
__device__ __forceinline__ float bflo(uint u) { return __uint_as_float(u << 16); }
__device__ __forceinline__ float bfhi(uint u) { return __uint_as_float(u & 0xFFFF0000u); }

// ---- 1a: degree histogram
__global__ __launch_bounds__(256) void k_deg(
    const int* __restrict__ ei, int* __restrict__ degi)
{
    int e = blockIdx.x * 256 + threadIdx.x;
    if (e < N_EDGE) atomicAdd(&degi[ei[N_EDGE + e]], 1);
}

// ---- 1b: exclusive scan (single block, 1024 threads)
__global__ __launch_bounds__(1024) void k_scan(
    const int* __restrict__ degi, int* __restrict__ rowptr, int* __restrict__ fillc)
{
    __shared__ int part[1024];
    int t = threadIdx.x;
    const int CH = 49;                          // 1024*49 >= N_ENT
    int lo = t * CH, hi = min(lo + CH, N_ENT);
    int s = 0;
    for (int i = lo; i < hi; ++i) s += degi[i];
    part[t] = s;
    __syncthreads();
    for (int off = 1; off < 1024; off <<= 1) {
        int v = (t >= off) ? part[t - off] : 0;
        __syncthreads();
        part[t] += v;
        __syncthreads();
    }
    int run = (t == 0) ? 0 : part[t - 1];
    for (int i = lo; i < hi; ++i) {
        rowptr[i] = run;
        fillc[i]  = run;
        run += degi[i];
    }
    if (t == 1023) rowptr[N_ENT] = run;
}

// ---- 1c: bucket-fill packed (src | type<<16)
__global__ __launch_bounds__(256) void k_fill(
    const int* __restrict__ ei, const int* __restrict__ et,
    int* __restrict__ fillc, int* __restrict__ packed)
{
    int e = blockIdx.x * 256 + threadIdx.x;
    if (e >= N_EDGE) return;
    int dst = ei[N_EDGE + e];
    int pos = atomicAdd(&fillc[dst], 1);
    packed[pos] = ei[e] | (et[e] << 16);
}

// ---- prep: transpose+convert weights to bf16 [N][K]; rel -> bf16
__global__ __launch_bounds__(256) void k_wprep(
    const float* __restrict__ Wm, const float* __restrict__ Wsf,
    const float* __restrict__ W1, const float* __restrict__ W2,
    const float* __restrict__ rel,
    ushort* __restrict__ Wt1, ushort* __restrict__ W1t,
    ushort* __restrict__ W2t, ushort* __restrict__ relb)
{
    int idx = blockIdx.x * 256 + threadIdx.x;
    if (idx < 65536) {                 // Wt1[n][k] = k<128 ? Wm[k][n] : Wsf[k-128][n]
        int n = idx >> 8, k = idx & 255;
        float v = (k < FEAT) ? Wm[k * HID + n] : Wsf[(k - FEAT) * HID + n];
        Wt1[idx] = f2bf(v);
    } else if (idx < 131072) {         // W1t[n][k] = W1[k][n]
        int o = idx - 65536;
        int n = o >> 8, k = o & 255;
        W1t[o] = f2bf(W1[k * HID + n]);
    } else if (idx < 163840) {         // W2t[n][k] = W2[k][n]
        int o = idx - 131072;
        int n = o >> 8, k = o & 255;
        W2t[o] = f2bf(W2[k * OUT_D + n]);
    } else if (idx < 163840 + 101 * 128) {
        int o = idx - 163840;
        relb[o] = f2bf(rel[o]);
    }
}

// ---- cvt: x (f32) -> right half of A (bf16)
__global__ __launch_bounds__(256) void k_cvt(
    const float* __restrict__ x, ushort* __restrict__ A)
{
    int idx = blockIdx.x * 256 + threadIdx.x;   // 800,000 threads, 8 elems each
    int m = idx >> 4;
    int c = (idx & 15) * 8;
    float4 f0 = *(const float4*)(x + m * FEAT + c);
    float4 f1 = *(const float4*)(x + m * FEAT + c + 4);
    uint4 o;
    o.x = (uint)f2bf(f0.x) | ((uint)f2bf(f0.y) << 16);
    o.y = (uint)f2bf(f0.z) | ((uint)f2bf(f0.w) << 16);
    o.z = (uint)f2bf(f1.x) | ((uint)f2bf(f1.y) << 16);
    o.w = (uint)f2bf(f1.z) | ((uint)f2bf(f1.w) << 16);
    *(uint4*)(A + m * 256 + FEAT + c) = o;
}

// ---- agg: segment mean over bf16 gathers -> left half of A (bf16)
__global__ __launch_bounds__(256) void k_agg(
    const int* __restrict__ rowptr, const int* __restrict__ packed,
    ushort* __restrict__ A, const ushort* __restrict__ relb)
{
    int node = blockIdx.x * 4 + (threadIdx.x >> 6);
    int lane = threadIdx.x & 63;
    int e0 = rowptr[node], e1 = rowptr[node + 1];
    float ax = 0.f, ay = 0.f;
    for (int e = e0; e < e1; ++e) {
        int p   = packed[e];
        int src = p & 0xFFFF;
        int typ = p >> 16;
        uint xv = *(const uint*)(A + src * 256 + FEAT + lane * 2);
        uint rv = *(const uint*)(relb + typ * FEAT + lane * 2);
        ax += bflo(xv) + bflo(rv);
        ay += bfhi(xv) + bfhi(rv);
    }
    float invd = 1.0f / fmaxf((float)(e1 - e0), 1.0f);
    uint o = (uint)f2bf(ax * invd) | ((uint)f2bf(ay * invd) << 16);
    *(uint*)(A + node * 256 + lane * 2) = o;
}

// ---- hy: h = A@Wt1^T + bm ; y = h@W1t^T + b1 ; col stats. 64 rows/block, 4 waves.
__global__ __launch_bounds__(256) void k_hy(
    const ushort* __restrict__ A, const ushort* __restrict__ Wt1,
    const ushort* __restrict__ W1t,
    const float* __restrict__ bm, const float* __restrict__ b1,
    ushort* __restrict__ y, float* __restrict__ colsum, float* __restrict__ colsq)
{
    __shared__ ushort h_s[64 * 256];      // 32 KB, XOR-swizzled 16B granules
    int tid = threadIdx.x;
    int w = tid >> 6, l = tid & 63;
    int lr = l & 15, lk = l >> 4;
    int m0 = blockIdx.x * 64;

    // ---- phase 1: h = [agg|x] @ [Wm;Wsf] (+bm)
    f32x4 acc[4][4] = {};
    const ushort* Ap = A + (m0 + lr) * 256 + lk * 8;
    const ushort* Bp = Wt1 + (w * 64 + lr) * 256 + lk * 8;
    for (int k0 = 0; k0 < 256; k0 += 32) {
        bf16x8 a[4], b[4];
        #pragma unroll
        for (int mb = 0; mb < 4; ++mb) a[mb] = *(const bf16x8*)(Ap + mb * 16 * 256 + k0);
        #pragma unroll
        for (int nb = 0; nb < 4; ++nb) b[nb] = *(const bf16x8*)(Bp + nb * 16 * 256 + k0);
        #pragma unroll
        for (int mb = 0; mb < 4; ++mb)
            #pragma unroll
            for (int nb = 0; nb < 4; ++nb)
                acc[mb][nb] = __builtin_amdgcn_mfma_f32_16x16x32_bf16(a[mb], b[nb], acc[mb][nb], 0, 0, 0);
    }
    #pragma unroll
    for (int nb = 0; nb < 4; ++nb) {
        int col = w * 64 + nb * 16 + lr;
        float bias = bm[col];
        #pragma unroll
        for (int mb = 0; mb < 4; ++mb)
            #pragma unroll
            for (int r = 0; r < 4; ++r) {
                int row = mb * 16 + lk * 4 + r;
                h_s[row * 256 + (col ^ ((row & 7) << 3))] = f2bf(acc[mb][nb][r] + bias);
            }
    }
    __syncthreads();

    // ---- phase 2: y = h @ W1 (+b1)
    f32x4 acc2[4][4] = {};
    const ushort* B2p = W1t + (w * 64 + lr) * 256 + lk * 8;
    for (int k0 = 0; k0 < 256; k0 += 32) {
        bf16x8 a[4], b[4];
        #pragma unroll
        for (int mb = 0; mb < 4; ++mb) {
            int row = mb * 16 + lr;
            a[mb] = *(const bf16x8*)&h_s[row * 256 + ((k0 + lk * 8) ^ ((row & 7) << 3))];
        }
        #pragma unroll
        for (int nb = 0; nb < 4; ++nb) b[nb] = *(const bf16x8*)(B2p + nb * 16 * 256 + k0);
        #pragma unroll
        for (int mb = 0; mb < 4; ++mb)
            #pragma unroll
            for (int nb = 0; nb < 4; ++nb)
                acc2[mb][nb] = __builtin_amdgcn_mfma_f32_16x16x32_bf16(a[mb], b[nb], acc2[mb][nb], 0, 0, 0);
    }
    __syncthreads();   // all h_s reads done; reuse h_s as y staging

    #pragma unroll
    for (int nb = 0; nb < 4; ++nb) {
        int col = w * 64 + nb * 16 + lr;
        float b1v = b1[col];
        float cs = 0.f, cq = 0.f;
        #pragma unroll
        for (int mb = 0; mb < 4; ++mb)
            #pragma unroll
            for (int r = 0; r < 4; ++r) {
                int row = mb * 16 + lk * 4 + r;
                float v = acc2[mb][nb][r] + b1v;
                if (m0 + row < N_ENT) { cs += v; cq += v * v; }
                h_s[row * 256 + (col ^ ((row & 7) << 3))] = f2bf(v);
            }
        // reduce across the 4 lanes (lk) sharing this col, then one atomic
        cs += __shfl_xor(cs, 16); cs += __shfl_xor(cs, 32);
        cq += __shfl_xor(cq, 16); cq += __shfl_xor(cq, 32);
        if (lk == 0) {
            atomicAdd(colsum + col, cs);
            atomicAdd(colsq  + col, cq);
        }
    }
    __syncthreads();
    // linear copy to global y (keeps swizzled granule layout)
    ushort* yp = y + m0 * 256;
    #pragma unroll
    for (int i = 0; i < 8; ++i) {
        int off = i * 2048 + tid * 8;
        *(uint4*)(yp + off) = *(const uint4*)&h_s[off];
    }
}

// ---- stats -> scale/shift
__global__ __launch_bounds__(256) void k_stats(
    const float* __restrict__ colsum, const float* __restrict__ colsq,
    const float* __restrict__ gamma,  const float* __restrict__ beta,
    float* __restrict__ scale, float* __restrict__ shift)
{
    int c = threadIdx.x;
    const float invn = 1.0f / (float)N_ENT;
    float mean = colsum[c] * invn;
    float var  = colsq[c] * invn - mean * mean;
    float rstd = rsqrtf(var + BN_EPS);
    float sc   = gamma[c] * rstd;
    scale[c] = sc;
    shift[c] = beta[c] - mean * sc;
}

// ---- zout: out = relu(y*scale+shift) @ W2 + b2. 64 rows/block, 4 waves x 32 cols.
__global__ __launch_bounds__(256) void k_zout(
    const ushort* __restrict__ y, const float* __restrict__ scale,
    const float* __restrict__ shift, const ushort* __restrict__ W2t,
    const float* __restrict__ b2, float* __restrict__ out)
{
    int tid = threadIdx.x;
    int w = tid >> 6, l = tid & 63;
    int lr = l & 15, lk = l >> 4;
    int m0 = blockIdx.x * 64;

    f32x4 acc[4][2] = {};
    const ushort* Bp = W2t + (w * 32 + lr) * 256 + lk * 8;
    for (int k0 = 0; k0 < 256; k0 += 32) {
        int kb = k0 + lk * 8;
        float scv[8], shv[8];
        *(float4*)&scv[0] = *(const float4*)(scale + kb);
        *(float4*)&scv[4] = *(const float4*)(scale + kb + 4);
        *(float4*)&shv[0] = *(const float4*)(shift + kb);
        *(float4*)&shv[4] = *(const float4*)(shift + kb + 4);
        bf16x8 b[2];
        #pragma unroll
        for (int nb = 0; nb < 2; ++nb) b[nb] = *(const bf16x8*)(Bp + nb * 16 * 256 + k0);
        bf16x8 a[4];
        #pragma unroll
        for (int mb = 0; mb < 4; ++mb) {
            int row = m0 + mb * 16 + lr;
            uint4 uv = *(const uint4*)(y + row * 256 + (kb ^ ((row & 7) << 3)));
            uint wd[4] = {uv.x, uv.y, uv.z, uv.w};
            #pragma unroll
            for (int j = 0; j < 8; ++j) {
                uint bits = (j & 1) ? (wd[j >> 1] & 0xFFFF0000u) : (wd[j >> 1] << 16);
                float f = __uint_as_float(bits);
                float z = fmaxf(f * scv[j] + shv[j], 0.f);
                a[mb][j] = (short)f2bf(z);
            }
        }
        #pragma unroll
        for (int mb = 0; mb < 4; ++mb)
            #pragma unroll
            for (int nb = 0; nb < 2; ++nb)
                acc[mb][nb] = __builtin_amdgcn_mfma_f32_16x16x32_bf16(a[mb], b[nb], acc[mb][nb], 0, 0, 0);
    }
    #pragma unroll
    for (int nb = 0; nb < 2; ++nb) {
        int col = w * 32 + nb * 16 + lr;
        float b2v = b2[col];
        #pragma unroll
        for (int mb = 0; mb < 4; ++mb)
            #pragma unroll
            for (int r = 0; r < 4; ++r) {
                int row = m0 + mb * 16 + lk * 4 + r;
                if (row < N_ENT) out[row * OUT_D + col] = acc[mb][nb][r] + b2v;
            }
    }
}

extern "C" void kernel_launch(void* const* d_in, const int* in_sizes, int n_in,
                              void* d_out, int out_size, void* d_ws, size_t ws_size,
                              hipStream_t stream)
{
    const int*   ei    = (const int*)d_in[0];
    const int*   et    = (const int*)d_in[1];
    const float* x     = (const float*)d_in[2];
    const float* rel   = (const float*)d_in[3];
    const float* Wm    = (const float*)d_in[4];
    const float* bm    = (const float*)d_in[5];
    const float* Wsf   = (const float*)d_in[6];
    const float* W1    = (const float*)d_in[7];
    const float* b1    = (const float*)d_in[8];
    const float* gamma = (const float*)d_in[9];
    const float* beta  = (const float*)d_in[10];
    const float* W2    = (const float*)d_in[11];
    const float* b2    = (const float*)d_in[12];
    float* out = (float*)d_out;

    char* ws = (char*)d_ws;
    int*    degi   = (int*)(ws + OFF_DEGI);
    float*  colsum = (float*)(ws + OFF_COLSUM);
    float*  colsq  = (float*)(ws + OFF_COLSQ);
    float*  scale  = (float*)(ws + OFF_SCALE);
    float*  shift  = (float*)(ws + OFF_SHIFT);
    ushort* relb   = (ushort*)(ws + OFF_RELB);
    ushort* Wt1    = (ushort*)(ws + OFF_WT1);
    ushort* W1t    = (ushort*)(ws + OFF_W1T);
    ushort* W2t    = (ushort*)(ws + OFF_W2T);
    ushort* A      = (ushort*)(ws + OFF_A);
    ushort* y      = (ushort*)(ws + OFF_Y);
    int*    rowptr = (int*)(ws + OFF_ROWPTR);
    int*    fillc  = (int*)(ws + OFF_FILLC);
    int*    packed = (int*)(ws + OFF_PACKED);

    // zero degi/colsum/colsq + A pad rows
    hipMemsetAsync(ws + OFF_DEGI, 0, 202048, stream);
    hipMemsetAsync(ws + OFF_A + N_ENT * 512, 0, (MROWS - N_ENT) * 512, stream);

    k_deg  <<<(N_EDGE + 255) / 256, 256, 0, stream>>>(ei, degi);
    k_wprep<<<691, 256, 0, stream>>>(Wm, Wsf, W1, W2, rel, Wt1, W1t, W2t, relb);
    k_cvt  <<<3125, 256, 0, stream>>>(x, A);
    k_scan <<<1, 1024, 0, stream>>>(degi, rowptr, fillc);
    k_fill <<<(N_EDGE + 255) / 256, 256, 0, stream>>>(ei, et, fillc, packed);
    k_agg  <<<N_ENT / 4, 256, 0, stream>>>(rowptr, packed, A, relb);
    k_hy   <<<MROWS / 64, 256, 0, stream>>>(A, Wt1, W1t, bm, b1, y, colsum, colsq);
    k_stats<<<1, 256, 0, stream>>>(colsum, colsq, gamma, beta, scale, shift);
    k_zout <<<MROWS / 64, 256, 0, stream>>>(y, scale, shift, W2t, b2, out);
}

// Round 4
// 214.583 us; speedup vs baseline: 4.0366x; 1.5756x over previous
//
#include <hip/hip_runtime.h>
#include <hip/hip_bf16.h>

#define N_ENT   50000
#define N_EDGE  600000
#define FEAT    128
#define HID     256
#define OUT_D   128
#define MROWS   50048        // N_ENT padded to 64
#define BN_EPS  1e-5f
#define SCAN_BLKS 196        // ceil(N_ENT/256)

// ---------------- ws layout (bytes) ----------------
#define OFF_DEGI    0               // [N_ENT] i32          200,000
#define OFF_COLSUM  200000          // [HID] f32            1,024
#define OFF_COLSQ   201024          // [HID] f32            1,024
#define OFF_SCALE   202048          // [HID] f32            1,024
#define OFF_SHIFT   203072          // [HID] f32            1,024
#define OFF_RELB    204096          // [101][128] bf16      25,856
#define OFF_WT1     229952          // [256][256] bf16 (WmWsf^T stacked)  131,072
#define OFF_W1T     361024          // [256][256] bf16      131,072
#define OFF_W2T     492096          // [128][256] bf16      65,536
#define OFF_A       557632          // [MROWS][256] bf16 ([agg|x])  25,624,576
#define OFF_Y       26182208        // [MROWS][256] bf16 (swizzled granules) 25,624,576
// CSR + scan scratch overlay head of Y region (consumed before k_hy writes y):
#define OFF_ROWPTR  26182208
#define OFF_FILLC   (26182208 + 200064)
#define OFF_PACKED  (26182208 + 400064)
#define OFF_BSUM    (26182208 + 2800064)   // [196] i32
#define OFF_BOFF    (26182208 + 2801088)   // [196] i32

typedef __attribute__((ext_vector_type(8))) short bf16x8;
typedef __attribute__((ext_vector_type(4))) float f32x4;

__device__ __forceinline__ ushort f2bf(float f) {
    uint u = __float_as_uint(f);
    return (ushort)((u + 0x7FFFu + ((u >> 16) & 1u)) >> 16);
}
__device__ __forceinline__ float bflo(uint u) { return __uint_as_float(u << 16); }
__device__ __forceinline__ float bfhi(uint u) { return __uint_as_float(u & 0xFFFF0000u); }

// ---- 1a: degree histogram
__global__ __launch_bounds__(256) void k_deg(
    const int* __restrict__ ei, int* __restrict__ degi)
{
    int e = blockIdx.x * 256 + threadIdx.x;
    if (e < N_EDGE) atomicAdd(&degi[ei[N_EDGE + e]], 1);
}

// ---- 1b-i: per-block sums of degi
__global__ __launch_bounds__(256) void k_bsum(
    const int* __restrict__ degi, int* __restrict__ bsum)
{
    __shared__ int red[4];
    int idx = blockIdx.x * 256 + threadIdx.x;
    int v = (idx < N_ENT) ? degi[idx] : 0;
    #pragma unroll
    for (int off = 1; off < 64; off <<= 1) v += __shfl_xor(v, off);
    if ((threadIdx.x & 63) == 0) red[threadIdx.x >> 6] = v;
    __syncthreads();
    if (threadIdx.x == 0) bsum[blockIdx.x] = red[0] + red[1] + red[2] + red[3];
}

// ---- 1b-ii: scan block sums -> block offsets (single 256-thread block)
__global__ __launch_bounds__(256) void k_boff(
    const int* __restrict__ bsum, int* __restrict__ boff, int* __restrict__ rowptr)
{
    __shared__ int s[256];
    int t = threadIdx.x;
    int v = (t < SCAN_BLKS) ? bsum[t] : 0;
    s[t] = v;
    __syncthreads();
    for (int off = 1; off < 256; off <<= 1) {
        int u = (t >= off) ? s[t - off] : 0;
        __syncthreads();
        s[t] += u;
        __syncthreads();
    }
    if (t < SCAN_BLKS) boff[t] = s[t] - v;
    if (t == 255) rowptr[N_ENT] = s[255];
}

// ---- 1b-iii: in-block exclusive scan + block offset -> rowptr, fillc
__global__ __launch_bounds__(256) void k_scan2(
    const int* __restrict__ degi, const int* __restrict__ boff,
    int* __restrict__ rowptr, int* __restrict__ fillc)
{
    __shared__ int s[256];
    int t = threadIdx.x;
    int idx = blockIdx.x * 256 + t;
    int v = (idx < N_ENT) ? degi[idx] : 0;
    s[t] = v;
    __syncthreads();
    for (int off = 1; off < 256; off <<= 1) {
        int u = (t >= off) ? s[t - off] : 0;
        __syncthreads();
        s[t] += u;
        __syncthreads();
    }
    if (idx < N_ENT) {
        int ex = s[t] - v + boff[blockIdx.x];
        rowptr[idx] = ex;
        fillc[idx]  = ex;
    }
}

// ---- 1c: bucket-fill packed (src | type<<16)
__global__ __launch_bounds__(256) void k_fill(
    const int* __restrict__ ei, const int* __restrict__ et,
    int* __restrict__ fillc, int* __restrict__ packed)
{
    int e = blockIdx.x * 256 + threadIdx.x;
    if (e >= N_EDGE) return;
    int dst = ei[N_EDGE + e];
    int pos = atomicAdd(&fillc[dst], 1);
    packed[pos] = ei[e] | (et[e] << 16);
}

// ---- prep: transpose+convert weights to bf16 [N][K]; rel -> bf16
__global__ __launch_bounds__(256) void k_wprep(
    const float* __restrict__ Wm, const float* __restrict__ Wsf,
    const float* __restrict__ W1, const float* __restrict__ W2,
    const float* __restrict__ rel,
    ushort* __restrict__ Wt1, ushort* __restrict__ W1t,
    ushort* __restrict__ W2t, ushort* __restrict__ relb)
{
    int idx = blockIdx.x * 256 + threadIdx.x;
    if (idx < 65536) {                 // Wt1[n][k] = k<128 ? Wm[k][n] : Wsf[k-128][n]
        int n = idx >> 8, k = idx & 255;
        float v = (k < FEAT) ? Wm[k * HID + n] : Wsf[(k - FEAT) * HID + n];
        Wt1[idx] = f2bf(v);
    } else if (idx < 131072) {         // W1t[n][k] = W1[k][n]
        int o = idx - 65536;
        int n = o >> 8, k = o & 255;
        W1t[o] = f2bf(W1[k * HID + n]);
    } else if (idx < 163840) {         // W2t[n][k] = W2[k][n]
        int o = idx - 131072;
        int n = o >> 8, k = o & 255;
        W2t[o] = f2bf(W2[k * OUT_D + n]);
    } else if (idx < 163840 + 101 * 128) {
        int o = idx - 163840;
        relb[o] = f2bf(rel[o]);
    }
}

// ---- cvt: x (f32) -> right half of A (bf16)
__global__ __launch_bounds__(256) void k_cvt(
    const float* __restrict__ x, ushort* __restrict__ A)
{
    int idx = blockIdx.x * 256 + threadIdx.x;   // 800,000 threads, 8 elems each
    int m = idx >> 4;
    int c = (idx & 15) * 8;
    float4 f0 = *(const float4*)(x + m * FEAT + c);
    float4 f1 = *(const float4*)(x + m * FEAT + c + 4);
    uint4 o;
    o.x = (uint)f2bf(f0.x) | ((uint)f2bf(f0.y) << 16);
    o.y = (uint)f2bf(f0.z) | ((uint)f2bf(f0.w) << 16);
    o.z = (uint)f2bf(f1.x) | ((uint)f2bf(f1.y) << 16);
    o.w = (uint)f2bf(f1.z) | ((uint)f2bf(f1.w) << 16);
    *(uint4*)(A + m * 256 + FEAT + c) = o;
}

// ---- agg: segment mean over bf16 gathers -> left half of A (bf16)
__global__ __launch_bounds__(256) void k_agg(
    const int* __restrict__ rowptr, const int* __restrict__ packed,
    ushort* __restrict__ A, const ushort* __restrict__ relb)
{
    int node = blockIdx.x * 4 + (threadIdx.x >> 6);
    int lane = threadIdx.x & 63;
    int e0 = rowptr[node], e1 = rowptr[node + 1];
    float ax = 0.f, ay = 0.f;
    int e = e0;
    for (; e + 2 <= e1; e += 2) {       // 2-deep MLP: 4 independent loads in flight
        int p0 = packed[e], p1 = packed[e + 1];
        uint xv0 = *(const uint*)(A + (p0 & 0xFFFF) * 256 + FEAT + lane * 2);
        uint rv0 = *(const uint*)(relb + (p0 >> 16) * FEAT + lane * 2);
        uint xv1 = *(const uint*)(A + (p1 & 0xFFFF) * 256 + FEAT + lane * 2);
        uint rv1 = *(const uint*)(relb + (p1 >> 16) * FEAT + lane * 2);
        ax += bflo(xv0) + bflo(rv0);
        ay += bfhi(xv0) + bfhi(rv0);
        ax += bflo(xv1) + bflo(rv1);
        ay += bfhi(xv1) + bfhi(rv1);
    }
    if (e < e1) {
        int p = packed[e];
        uint xv = *(const uint*)(A + (p & 0xFFFF) * 256 + FEAT + lane * 2);
        uint rv = *(const uint*)(relb + (p >> 16) * FEAT + lane * 2);
        ax += bflo(xv) + bflo(rv);
        ay += bfhi(xv) + bfhi(rv);
    }
    float invd = 1.0f / fmaxf((float)(e1 - e0), 1.0f);
    uint o = (uint)f2bf(ax * invd) | ((uint)f2bf(ay * invd) << 16);
    *(uint*)(A + node * 256 + lane * 2) = o;
}

// ---- hy: h = A@Wt1^T + bm ; y = h@W1t^T + b1 ; col stats. 64 rows/block, 4 waves.
__global__ __launch_bounds__(256) void k_hy(
    const ushort* __restrict__ A, const ushort* __restrict__ Wt1,
    const ushort* __restrict__ W1t,
    const float* __restrict__ bm, const float* __restrict__ b1,
    ushort* __restrict__ y, float* __restrict__ colsum, float* __restrict__ colsq)
{
    __shared__ ushort h_s[64 * 256];      // 32 KB, XOR-swizzled 16B granules
    int tid = threadIdx.x;
    int w = tid >> 6, l = tid & 63;
    int lr = l & 15, lk = l >> 4;
    int m0 = blockIdx.x * 64;

    // ---- phase 1: h = [agg|x] @ [Wm;Wsf] (+bm)
    f32x4 acc[4][4] = {};
    const ushort* Ap = A + (m0 + lr) * 256 + lk * 8;
    const ushort* Bp = Wt1 + (w * 64 + lr) * 256 + lk * 8;
    for (int k0 = 0; k0 < 256; k0 += 32) {
        bf16x8 a[4], b[4];
        #pragma unroll
        for (int mb = 0; mb < 4; ++mb) a[mb] = *(const bf16x8*)(Ap + mb * 16 * 256 + k0);
        #pragma unroll
        for (int nb = 0; nb < 4; ++nb) b[nb] = *(const bf16x8*)(Bp + nb * 16 * 256 + k0);
        #pragma unroll
        for (int mb = 0; mb < 4; ++mb)
            #pragma unroll
            for (int nb = 0; nb < 4; ++nb)
                acc[mb][nb] = __builtin_amdgcn_mfma_f32_16x16x32_bf16(a[mb], b[nb], acc[mb][nb], 0, 0, 0);
    }
    #pragma unroll
    for (int nb = 0; nb < 4; ++nb) {
        int col = w * 64 + nb * 16 + lr;
        float bias = bm[col];
        #pragma unroll
        for (int mb = 0; mb < 4; ++mb)
            #pragma unroll
            for (int r = 0; r < 4; ++r) {
                int row = mb * 16 + lk * 4 + r;
                h_s[row * 256 + (col ^ ((row & 7) << 3))] = f2bf(acc[mb][nb][r] + bias);
            }
    }
    __syncthreads();

    // ---- phase 2: y = h @ W1 (+b1)
    f32x4 acc2[4][4] = {};
    const ushort* B2p = W1t + (w * 64 + lr) * 256 + lk * 8;
    for (int k0 = 0; k0 < 256; k0 += 32) {
        bf16x8 a[4], b[4];
        #pragma unroll
        for (int mb = 0; mb < 4; ++mb) {
            int row = mb * 16 + lr;
            a[mb] = *(const bf16x8*)&h_s[row * 256 + ((k0 + lk * 8) ^ ((row & 7) << 3))];
        }
        #pragma unroll
        for (int nb = 0; nb < 4; ++nb) b[nb] = *(const bf16x8*)(B2p + nb * 16 * 256 + k0);
        #pragma unroll
        for (int mb = 0; mb < 4; ++mb)
            #pragma unroll
            for (int nb = 0; nb < 4; ++nb)
                acc2[mb][nb] = __builtin_amdgcn_mfma_f32_16x16x32_bf16(a[mb], b[nb], acc2[mb][nb], 0, 0, 0);
    }
    __syncthreads();   // all h_s reads done; reuse h_s as y staging

    #pragma unroll
    for (int nb = 0; nb < 4; ++nb) {
        int col = w * 64 + nb * 16 + lr;
        float b1v = b1[col];
        float cs = 0.f, cq = 0.f;
        #pragma unroll
        for (int mb = 0; mb < 4; ++mb)
            #pragma unroll
            for (int r = 0; r < 4; ++r) {
                int row = mb * 16 + lk * 4 + r;
                float v = acc2[mb][nb][r] + b1v;
                if (m0 + row < N_ENT) { cs += v; cq += v * v; }
                h_s[row * 256 + (col ^ ((row & 7) << 3))] = f2bf(v);
            }
        cs += __shfl_xor(cs, 16); cs += __shfl_xor(cs, 32);
        cq += __shfl_xor(cq, 16); cq += __shfl_xor(cq, 32);
        if (lk == 0) {
            atomicAdd(colsum + col, cs);
            atomicAdd(colsq  + col, cq);
        }
    }
    __syncthreads();
    ushort* yp = y + m0 * 256;
    #pragma unroll
    for (int i = 0; i < 8; ++i) {
        int off = i * 2048 + tid * 8;
        *(uint4*)(yp + off) = *(const uint4*)&h_s[off];
    }
}

// ---- stats -> scale/shift
__global__ __launch_bounds__(256) void k_stats(
    const float* __restrict__ colsum, const float* __restrict__ colsq,
    const float* __restrict__ gamma,  const float* __restrict__ beta,
    float* __restrict__ scale, float* __restrict__ shift)
{
    int c = threadIdx.x;
    const float invn = 1.0f / (float)N_ENT;
    float mean = colsum[c] * invn;
    float var  = colsq[c] * invn - mean * mean;
    float rstd = rsqrtf(var + BN_EPS);
    float sc   = gamma[c] * rstd;
    scale[c] = sc;
    shift[c] = beta[c] - mean * sc;
}

// ---- zout: out = relu(y*scale+shift) @ W2 + b2. 64 rows/block, 4 waves x 32 cols.
__global__ __launch_bounds__(256) void k_zout(
    const ushort* __restrict__ y, const float* __restrict__ scale,
    const float* __restrict__ shift, const ushort* __restrict__ W2t,
    const float* __restrict__ b2, float* __restrict__ out)
{
    int tid = threadIdx.x;
    int w = tid >> 6, l = tid & 63;
    int lr = l & 15, lk = l >> 4;
    int m0 = blockIdx.x * 64;

    f32x4 acc[4][2] = {};
    const ushort* Bp = W2t + (w * 32 + lr) * 256 + lk * 8;
    for (int k0 = 0; k0 < 256; k0 += 32) {
        int kb = k0 + lk * 8;
        float scv[8], shv[8];
        *(float4*)&scv[0] = *(const float4*)(scale + kb);
        *(float4*)&scv[4] = *(const float4*)(scale + kb + 4);
        *(float4*)&shv[0] = *(const float4*)(shift + kb);
        *(float4*)&shv[4] = *(const float4*)(shift + kb + 4);
        bf16x8 b[2];
        #pragma unroll
        for (int nb = 0; nb < 2; ++nb) b[nb] = *(const bf16x8*)(Bp + nb * 16 * 256 + k0);
        bf16x8 a[4];
        #pragma unroll
        for (int mb = 0; mb < 4; ++mb) {
            int row = m0 + mb * 16 + lr;
            uint4 uv = *(const uint4*)(y + row * 256 + (kb ^ ((row & 7) << 3)));
            uint wd[4] = {uv.x, uv.y, uv.z, uv.w};
            #pragma unroll
            for (int j = 0; j < 8; ++j) {
                uint bits = (j & 1) ? (wd[j >> 1] & 0xFFFF0000u) : (wd[j >> 1] << 16);
                float f = __uint_as_float(bits);
                float z = fmaxf(f * scv[j] + shv[j], 0.f);
                a[mb][j] = (short)f2bf(z);
            }
        }
        #pragma unroll
        for (int mb = 0; mb < 4; ++mb)
            #pragma unroll
            for (int nb = 0; nb < 2; ++nb)
                acc[mb][nb] = __builtin_amdgcn_mfma_f32_16x16x32_bf16(a[mb], b[nb], acc[mb][nb], 0, 0, 0);
    }
    #pragma unroll
    for (int nb = 0; nb < 2; ++nb) {
        int col = w * 32 + nb * 16 + lr;
        float b2v = b2[col];
        #pragma unroll
        for (int mb = 0; mb < 4; ++mb)
            #pragma unroll
            for (int r = 0; r < 4; ++r) {
                int row = m0 + mb * 16 + lk * 4 + r;
                if (row < N_ENT) out[row * OUT_D + col] = acc[mb][nb][r] + b2v;
            }
    }
}

extern "C" void kernel_launch(void* const* d_in, const int* in_sizes, int n_in,
                              void* d_out, int out_size, void* d_ws, size_t ws_size,
                              hipStream_t stream)
{
    const int*   ei    = (const int*)d_in[0];
    const int*   et    = (const int*)d_in[1];
    const float* x     = (const float*)d_in[2];
    const float* rel   = (const float*)d_in[3];
    const float* Wm    = (const float*)d_in[4];
    const float* bm    = (const float*)d_in[5];
    const float* Wsf   = (const float*)d_in[6];
    const float* W1    = (const float*)d_in[7];
    const float* b1    = (const float*)d_in[8];
    const float* gamma = (const float*)d_in[9];
    const float* beta  = (const float*)d_in[10];
    const float* W2    = (const float*)d_in[11];
    const float* b2    = (const float*)d_in[12];
    float* out = (float*)d_out;

    char* ws = (char*)d_ws;
    int*    degi   = (int*)(ws + OFF_DEGI);
    float*  colsum = (float*)(ws + OFF_COLSUM);
    float*  colsq  = (float*)(ws + OFF_COLSQ);
    float*  scale  = (float*)(ws + OFF_SCALE);
    float*  shift  = (float*)(ws + OFF_SHIFT);
    ushort* relb   = (ushort*)(ws + OFF_RELB);
    ushort* Wt1    = (ushort*)(ws + OFF_WT1);
    ushort* W1t    = (ushort*)(ws + OFF_W1T);
    ushort* W2t    = (ushort*)(ws + OFF_W2T);
    ushort* A      = (ushort*)(ws + OFF_A);
    ushort* y      = (ushort*)(ws + OFF_Y);
    int*    rowptr = (int*)(ws + OFF_ROWPTR);
    int*    fillc  = (int*)(ws + OFF_FILLC);
    int*    packed = (int*)(ws + OFF_PACKED);
    int*    bsum   = (int*)(ws + OFF_BSUM);
    int*    boff   = (int*)(ws + OFF_BOFF);

    hipMemsetAsync(ws + OFF_DEGI, 0, 202048, stream);
    hipMemsetAsync(ws + OFF_A + N_ENT * 512, 0, (MROWS - N_ENT) * 512, stream);

    k_deg  <<<(N_EDGE + 255) / 256, 256, 0, stream>>>(ei, degi);
    k_wprep<<<691, 256, 0, stream>>>(Wm, Wsf, W1, W2, rel, Wt1, W1t, W2t, relb);
    k_cvt  <<<3125, 256, 0, stream>>>(x, A);
    k_bsum <<<SCAN_BLKS, 256, 0, stream>>>(degi, bsum);
    k_boff <<<1, 256, 0, stream>>>(bsum, boff, rowptr);
    k_scan2<<<SCAN_BLKS, 256, 0, stream>>>(degi, boff, rowptr, fillc);
    k_fill <<<(N_EDGE + 255) / 256, 256, 0, stream>>>(ei, et, fillc, packed);
    k_agg  <<<N_ENT / 4, 256, 0, stream>>>(rowptr, packed, A, relb);
    k_hy   <<<MROWS / 64, 256, 0, stream>>>(A, Wt1, W1t, bm, b1, y, colsum, colsq);
    k_stats<<<1, 256, 0, stream>>>(colsum, colsq, gamma, beta, scale, shift);
    k_zout <<<MROWS / 64, 256, 0, stream>>>(y, scale, shift, W2t, b2, out);
}

// Round 5
// 199.598 us; speedup vs baseline: 4.3397x; 1.0751x over previous
//
#include <hip/hip_runtime.h>
#include <hip/hip_bf16.h>

#define N_ENT   50000
#define N_EDGE  600000
#define FEAT    128
#define HID     256
#define OUT_D   128
#define MROWS   50048        // N_ENT padded to 64
#define BN_EPS  1e-5f
#define SCAN_BLKS 196        // ceil(N_ENT/256)

// ---------------- ws layout (bytes) ----------------
#define OFF_DEGI    0               // [N_ENT] i32          200,000
#define OFF_COLSUM  200000          // [HID] f32            1,024
#define OFF_COLSQ   201024          // [HID] f32            1,024
#define OFF_SCALE   202048          // [HID] f32            1,024
#define OFF_SHIFT   203072          // [HID] f32            1,024
#define OFF_RELB    204096          // [101][128] bf16      25,856
#define OFF_WT1     229952          // [256][256] bf16 (WmWsf^T stacked)  131,072
#define OFF_W1T     361024          // [256][256] bf16      131,072
#define OFF_W2T     492096          // [128][256] bf16      65,536
#define OFF_A       557632          // [MROWS][256] bf16 ([agg|x], linear)  25,624,576
#define OFF_Y       26182208        // [MROWS][256] bf16 (swizzled granules) 25,624,576
// CSR + scan scratch overlay head of Y region (consumed before k_hy writes y):
#define OFF_ROWPTR  26182208
#define OFF_FILLC   (26182208 + 200064)
#define OFF_PACKED  (26182208 + 400064)
#define OFF_BSUM    (26182208 + 2800064)   // [196] i32
#define OFF_BOFF    (26182208 + 2801088)   // [196] i32

typedef __attribute__((ext_vector_type(8))) short bf16x8;
typedef __attribute__((ext_vector_type(4))) float f32x4;

// async global->LDS, 16B per lane; lds base must be wave-uniform
#define GLL(gp, lp) __builtin_amdgcn_global_load_lds( \
    (const __attribute__((address_space(1))) void*)(gp), \
    (__attribute__((address_space(3))) void*)(lp), 16, 0, 0)

__device__ __forceinline__ ushort f2bf(float f) {
    uint u = __float_as_uint(f);
    return (ushort)((u + 0x7FFFu + ((u >> 16) & 1u)) >> 16);
}
__device__ __forceinline__ float bflo(uint u) { return __uint_as_float(u << 16); }
__device__ __forceinline__ float bfhi(uint u) { return __uint_as_float(u & 0xFFFF0000u); }

// ---- 1a: degree histogram
__global__ __launch_bounds__(256) void k_deg(
    const int* __restrict__ ei, int* __restrict__ degi)
{
    int e = blockIdx.x * 256 + threadIdx.x;
    if (e < N_EDGE) atomicAdd(&degi[ei[N_EDGE + e]], 1);
}

// ---- 1b-i: per-block sums of degi
__global__ __launch_bounds__(256) void k_bsum(
    const int* __restrict__ degi, int* __restrict__ bsum)
{
    __shared__ int red[4];
    int idx = blockIdx.x * 256 + threadIdx.x;
    int v = (idx < N_ENT) ? degi[idx] : 0;
    #pragma unroll
    for (int off = 1; off < 64; off <<= 1) v += __shfl_xor(v, off);
    if ((threadIdx.x & 63) == 0) red[threadIdx.x >> 6] = v;
    __syncthreads();
    if (threadIdx.x == 0) bsum[blockIdx.x] = red[0] + red[1] + red[2] + red[3];
}

// ---- 1b-ii: scan block sums -> block offsets
__global__ __launch_bounds__(256) void k_boff(
    const int* __restrict__ bsum, int* __restrict__ boff, int* __restrict__ rowptr)
{
    __shared__ int s[256];
    int t = threadIdx.x;
    int v = (t < SCAN_BLKS) ? bsum[t] : 0;
    s[t] = v;
    __syncthreads();
    for (int off = 1; off < 256; off <<= 1) {
        int u = (t >= off) ? s[t - off] : 0;
        __syncthreads();
        s[t] += u;
        __syncthreads();
    }
    if (t < SCAN_BLKS) boff[t] = s[t] - v;
    if (t == 255) rowptr[N_ENT] = s[255];
}

// ---- 1b-iii: in-block exclusive scan + block offset
__global__ __launch_bounds__(256) void k_scan2(
    const int* __restrict__ degi, const int* __restrict__ boff,
    int* __restrict__ rowptr, int* __restrict__ fillc)
{
    __shared__ int s[256];
    int t = threadIdx.x;
    int idx = blockIdx.x * 256 + t;
    int v = (idx < N_ENT) ? degi[idx] : 0;
    s[t] = v;
    __syncthreads();
    for (int off = 1; off < 256; off <<= 1) {
        int u = (t >= off) ? s[t - off] : 0;
        __syncthreads();
        s[t] += u;
        __syncthreads();
    }
    if (idx < N_ENT) {
        int ex = s[t] - v + boff[blockIdx.x];
        rowptr[idx] = ex;
        fillc[idx]  = ex;
    }
}

// ---- 1c: bucket-fill packed (src | type<<16)
__global__ __launch_bounds__(256) void k_fill(
    const int* __restrict__ ei, const int* __restrict__ et,
    int* __restrict__ fillc, int* __restrict__ packed)
{
    int e = blockIdx.x * 256 + threadIdx.x;
    if (e >= N_EDGE) return;
    int dst = ei[N_EDGE + e];
    int pos = atomicAdd(&fillc[dst], 1);
    packed[pos] = ei[e] | (et[e] << 16);
}

// ---- prep: transpose+convert weights to bf16 [N][K]; rel -> bf16
__global__ __launch_bounds__(256) void k_wprep(
    const float* __restrict__ Wm, const float* __restrict__ Wsf,
    const float* __restrict__ W1, const float* __restrict__ W2,
    const float* __restrict__ rel,
    ushort* __restrict__ Wt1, ushort* __restrict__ W1t,
    ushort* __restrict__ W2t, ushort* __restrict__ relb)
{
    int idx = blockIdx.x * 256 + threadIdx.x;
    if (idx < 65536) {
        int n = idx >> 8, k = idx & 255;
        float v = (k < FEAT) ? Wm[k * HID + n] : Wsf[(k - FEAT) * HID + n];
        Wt1[idx] = f2bf(v);
    } else if (idx < 131072) {
        int o = idx - 65536;
        int n = o >> 8, k = o & 255;
        W1t[o] = f2bf(W1[k * HID + n]);
    } else if (idx < 163840) {
        int o = idx - 131072;
        int n = o >> 8, k = o & 255;
        W2t[o] = f2bf(W2[k * OUT_D + n]);
    } else if (idx < 163840 + 101 * 128) {
        int o = idx - 163840;
        relb[o] = f2bf(rel[o]);
    }
}

// ---- cvt: x (f32) -> right half of A (bf16, linear)
__global__ __launch_bounds__(256) void k_cvt(
    const float* __restrict__ x, ushort* __restrict__ A)
{
    int idx = blockIdx.x * 256 + threadIdx.x;
    int m = idx >> 4;
    int c = (idx & 15) * 8;
    float4 f0 = *(const float4*)(x + m * FEAT + c);
    float4 f1 = *(const float4*)(x + m * FEAT + c + 4);
    uint4 o;
    o.x = (uint)f2bf(f0.x) | ((uint)f2bf(f0.y) << 16);
    o.y = (uint)f2bf(f0.z) | ((uint)f2bf(f0.w) << 16);
    o.z = (uint)f2bf(f1.x) | ((uint)f2bf(f1.y) << 16);
    o.w = (uint)f2bf(f1.z) | ((uint)f2bf(f1.w) << 16);
    *(uint4*)(A + m * 256 + FEAT + c) = o;
}

// ---- agg: segment mean over bf16 gathers -> left half of A (linear)
__global__ __launch_bounds__(256) void k_agg(
    const int* __restrict__ rowptr, const int* __restrict__ packed,
    ushort* __restrict__ A, const ushort* __restrict__ relb)
{
    int node = blockIdx.x * 4 + (threadIdx.x >> 6);
    int lane = threadIdx.x & 63;
    int e0 = rowptr[node], e1 = rowptr[node + 1];
    float ax = 0.f, ay = 0.f;
    int e = e0;
    for (; e + 4 <= e1; e += 4) {       // 4-deep MLP: 8 independent loads in flight
        int p0 = packed[e], p1 = packed[e + 1], p2 = packed[e + 2], p3 = packed[e + 3];
        uint xv0 = *(const uint*)(A + (p0 & 0xFFFF) * 256 + FEAT + lane * 2);
        uint rv0 = *(const uint*)(relb + (p0 >> 16) * FEAT + lane * 2);
        uint xv1 = *(const uint*)(A + (p1 & 0xFFFF) * 256 + FEAT + lane * 2);
        uint rv1 = *(const uint*)(relb + (p1 >> 16) * FEAT + lane * 2);
        uint xv2 = *(const uint*)(A + (p2 & 0xFFFF) * 256 + FEAT + lane * 2);
        uint rv2 = *(const uint*)(relb + (p2 >> 16) * FEAT + lane * 2);
        uint xv3 = *(const uint*)(A + (p3 & 0xFFFF) * 256 + FEAT + lane * 2);
        uint rv3 = *(const uint*)(relb + (p3 >> 16) * FEAT + lane * 2);
        ax += bflo(xv0) + bflo(rv0) + bflo(xv1) + bflo(rv1)
            + bflo(xv2) + bflo(rv2) + bflo(xv3) + bflo(rv3);
        ay += bfhi(xv0) + bfhi(rv0) + bfhi(xv1) + bfhi(rv1)
            + bfhi(xv2) + bfhi(rv2) + bfhi(xv3) + bfhi(rv3);
    }
    for (; e < e1; ++e) {
        int p = packed[e];
        uint xv = *(const uint*)(A + (p & 0xFFFF) * 256 + FEAT + lane * 2);
        uint rv = *(const uint*)(relb + (p >> 16) * FEAT + lane * 2);
        ax += bflo(xv) + bflo(rv);
        ay += bfhi(xv) + bfhi(rv);
    }
    float invd = 1.0f / fmaxf((float)(e1 - e0), 1.0f);
    uint o = (uint)f2bf(ax * invd) | ((uint)f2bf(ay * invd) << 16);
    *(uint*)(A + node * 256 + lane * 2) = o;
}

// ---- hy: h = A@Wt1^T + bm ; y = h@W1t^T + b1 ; col stats. 64 rows/block, 4 waves.
// A staged to LDS once (pre-swizzled source -> linear LDS = swizzled tile, rule #21);
// one 32KB buffer reused A -> h -> y.
__global__ __launch_bounds__(256) void k_hy(
    const ushort* __restrict__ A, const ushort* __restrict__ Wt1,
    const ushort* __restrict__ W1t,
    const float* __restrict__ bm, const float* __restrict__ b1,
    ushort* __restrict__ y, float* __restrict__ colsum, float* __restrict__ colsq)
{
    __shared__ ushort a_s[64 * 256];      // 32 KB; granule(16B) g at row r holds A[r][g ^ (r&7)]
    int tid = threadIdx.x;
    int w = tid >> 6, l = tid & 63;
    int lr = l & 15, lk = l >> 4;
    int m0 = blockIdx.x * 64;

    // ---- stage A-tile (each wave 8KB): LDS linear, global source swizzled
    {
        const ushort* srcb = A + (size_t)m0 * 256;
        #pragma unroll
        for (int j = 0; j < 8; ++j) {
            int slot = (w * 8 + j) * 64 + l;       // 16B slot index this lane fills
            int lrow = slot >> 5;                  // local row 0..63
            int lgr  = slot & 31;                  // LDS granule within row
            const ushort* gp = srcb + lrow * 256 + ((lgr ^ (lrow & 7)) << 3);
            GLL(gp, &a_s[(w * 8 + j) * 512]);
        }
    }
    __syncthreads();

    // ---- phase 1: h = [agg|x] @ [Wm;Wsf] (+bm); A from LDS, conflict-free
    f32x4 acc[4][4] = {};
    const ushort* Bp = Wt1 + (w * 64 + lr) * 256 + lk * 8;
    for (int k0 = 0; k0 < 256; k0 += 32) {
        bf16x8 a[4], b[4];
        #pragma unroll
        for (int mb = 0; mb < 4; ++mb) {
            int row = mb * 16 + lr;
            a[mb] = *(const bf16x8*)&a_s[row * 256 + ((((k0 >> 3) + lk) ^ (lr & 7)) << 3)];
        }
        #pragma unroll
        for (int nb = 0; nb < 4; ++nb) b[nb] = *(const bf16x8*)(Bp + nb * 16 * 256 + k0);
        #pragma unroll
        for (int mb = 0; mb < 4; ++mb)
            #pragma unroll
            for (int nb = 0; nb < 4; ++nb)
                acc[mb][nb] = __builtin_amdgcn_mfma_f32_16x16x32_bf16(a[mb], b[nb], acc[mb][nb], 0, 0, 0);
    }
    __syncthreads();   // all waves done reading A from a_s; reuse for h

    #pragma unroll
    for (int nb = 0; nb < 4; ++nb) {
        int col = w * 64 + nb * 16 + lr;
        float bias = bm[col];
        #pragma unroll
        for (int mb = 0; mb < 4; ++mb)
            #pragma unroll
            for (int r = 0; r < 4; ++r) {
                int row = mb * 16 + lk * 4 + r;
                a_s[row * 256 + (col ^ ((row & 7) << 3))] = f2bf(acc[mb][nb][r] + bias);
            }
    }
    __syncthreads();

    // ---- phase 2: y = h @ W1 (+b1)
    f32x4 acc2[4][4] = {};
    const ushort* B2p = W1t + (w * 64 + lr) * 256 + lk * 8;
    for (int k0 = 0; k0 < 256; k0 += 32) {
        bf16x8 a[4], b[4];
        #pragma unroll
        for (int mb = 0; mb < 4; ++mb) {
            int row = mb * 16 + lr;
            a[mb] = *(const bf16x8*)&a_s[row * 256 + ((k0 + lk * 8) ^ ((row & 7) << 3))];
        }
        #pragma unroll
        for (int nb = 0; nb < 4; ++nb) b[nb] = *(const bf16x8*)(B2p + nb * 16 * 256 + k0);
        #pragma unroll
        for (int mb = 0; mb < 4; ++mb)
            #pragma unroll
            for (int nb = 0; nb < 4; ++nb)
                acc2[mb][nb] = __builtin_amdgcn_mfma_f32_16x16x32_bf16(a[mb], b[nb], acc2[mb][nb], 0, 0, 0);
    }
    __syncthreads();   // all h reads done; reuse a_s for y staging

    #pragma unroll
    for (int nb = 0; nb < 4; ++nb) {
        int col = w * 64 + nb * 16 + lr;
        float b1v = b1[col];
        float cs = 0.f, cq = 0.f;
        #pragma unroll
        for (int mb = 0; mb < 4; ++mb)
            #pragma unroll
            for (int r = 0; r < 4; ++r) {
                int row = mb * 16 + lk * 4 + r;
                float v = acc2[mb][nb][r] + b1v;
                if (m0 + row < N_ENT) { cs += v; cq += v * v; }
                a_s[row * 256 + (col ^ ((row & 7) << 3))] = f2bf(v);
            }
        cs += __shfl_xor(cs, 16); cs += __shfl_xor(cs, 32);
        cq += __shfl_xor(cq, 16); cq += __shfl_xor(cq, 32);
        if (lk == 0) {
            atomicAdd(colsum + col, cs);
            atomicAdd(colsq  + col, cq);
        }
    }
    __syncthreads();
    ushort* yp = y + (size_t)m0 * 256;
    #pragma unroll
    for (int i = 0; i < 8; ++i) {
        int off = i * 2048 + tid * 8;
        *(uint4*)(yp + off) = *(const uint4*)&a_s[off];
    }
}

// ---- stats -> scale/shift
__global__ __launch_bounds__(256) void k_stats(
    const float* __restrict__ colsum, const float* __restrict__ colsq,
    const float* __restrict__ gamma,  const float* __restrict__ beta,
    float* __restrict__ scale, float* __restrict__ shift)
{
    int c = threadIdx.x;
    const float invn = 1.0f / (float)N_ENT;
    float mean = colsum[c] * invn;
    float var  = colsq[c] * invn - mean * mean;
    float rstd = rsqrtf(var + BN_EPS);
    float sc   = gamma[c] * rstd;
    scale[c] = sc;
    shift[c] = beta[c] - mean * sc;
}

// ---- zout: out = relu(y*scale+shift) @ W2 + b2. y-tile staged to LDS (linear copy,
// already swizzled in global).
__global__ __launch_bounds__(256) void k_zout(
    const ushort* __restrict__ y, const float* __restrict__ scale,
    const float* __restrict__ shift, const ushort* __restrict__ W2t,
    const float* __restrict__ b2, float* __restrict__ out)
{
    __shared__ ushort z_s[64 * 256];
    int tid = threadIdx.x;
    int w = tid >> 6, l = tid & 63;
    int lr = l & 15, lk = l >> 4;
    int m0 = blockIdx.x * 64;

    {
        const ushort* srcb = y + (size_t)m0 * 256;
        #pragma unroll
        for (int j = 0; j < 8; ++j) {
            const ushort* gp = srcb + ((w * 8 + j) * 64 + l) * 8;
            GLL(gp, &z_s[(w * 8 + j) * 512]);
        }
    }
    __syncthreads();

    f32x4 acc[4][2] = {};
    const ushort* Bp = W2t + (w * 32 + lr) * 256 + lk * 8;
    for (int k0 = 0; k0 < 256; k0 += 32) {
        int kb = k0 + lk * 8;
        float scv[8], shv[8];
        *(float4*)&scv[0] = *(const float4*)(scale + kb);
        *(float4*)&scv[4] = *(const float4*)(scale + kb + 4);
        *(float4*)&shv[0] = *(const float4*)(shift + kb);
        *(float4*)&shv[4] = *(const float4*)(shift + kb + 4);
        bf16x8 b[2];
        #pragma unroll
        for (int nb = 0; nb < 2; ++nb) b[nb] = *(const bf16x8*)(Bp + nb * 16 * 256 + k0);
        bf16x8 a[4];
        #pragma unroll
        for (int mb = 0; mb < 4; ++mb) {
            int row = mb * 16 + lr;
            uint4 uv = *(const uint4*)&z_s[row * 256 + (kb ^ ((row & 7) << 3))];
            uint wd[4] = {uv.x, uv.y, uv.z, uv.w};
            #pragma unroll
            for (int j = 0; j < 8; ++j) {
                uint bits = (j & 1) ? (wd[j >> 1] & 0xFFFF0000u) : (wd[j >> 1] << 16);
                float f = __uint_as_float(bits);
                float z = fmaxf(f * scv[j] + shv[j], 0.f);
                a[mb][j] = (short)f2bf(z);
            }
        }
        #pragma unroll
        for (int mb = 0; mb < 4; ++mb)
            #pragma unroll
            for (int nb = 0; nb < 2; ++nb)
                acc[mb][nb] = __builtin_amdgcn_mfma_f32_16x16x32_bf16(a[mb], b[nb], acc[mb][nb], 0, 0, 0);
    }
    #pragma unroll
    for (int nb = 0; nb < 2; ++nb) {
        int col = w * 32 + nb * 16 + lr;
        float b2v = b2[col];
        #pragma unroll
        for (int mb = 0; mb < 4; ++mb)
            #pragma unroll
            for (int r = 0; r < 4; ++r) {
                int row = m0 + mb * 16 + lk * 4 + r;
                if (row < N_ENT) out[row * OUT_D + col] = acc[mb][nb][r] + b2v;
            }
    }
}

extern "C" void kernel_launch(void* const* d_in, const int* in_sizes, int n_in,
                              void* d_out, int out_size, void* d_ws, size_t ws_size,
                              hipStream_t stream)
{
    const int*   ei    = (const int*)d_in[0];
    const int*   et    = (const int*)d_in[1];
    const float* x     = (const float*)d_in[2];
    const float* rel   = (const float*)d_in[3];
    const float* Wm    = (const float*)d_in[4];
    const float* bm    = (const float*)d_in[5];
    const float* Wsf   = (const float*)d_in[6];
    const float* W1    = (const float*)d_in[7];
    const float* b1    = (const float*)d_in[8];
    const float* gamma = (const float*)d_in[9];
    const float* beta  = (const float*)d_in[10];
    const float* W2    = (const float*)d_in[11];
    const float* b2    = (const float*)d_in[12];
    float* out = (float*)d_out;

    char* ws = (char*)d_ws;
    int*    degi   = (int*)(ws + OFF_DEGI);
    float*  colsum = (float*)(ws + OFF_COLSUM);
    float*  colsq  = (float*)(ws + OFF_COLSQ);
    float*  scale  = (float*)(ws + OFF_SCALE);
    float*  shift  = (float*)(ws + OFF_SHIFT);
    ushort* relb   = (ushort*)(ws + OFF_RELB);
    ushort* Wt1    = (ushort*)(ws + OFF_WT1);
    ushort* W1t    = (ushort*)(ws + OFF_W1T);
    ushort* W2t    = (ushort*)(ws + OFF_W2T);
    ushort* A      = (ushort*)(ws + OFF_A);
    ushort* y      = (ushort*)(ws + OFF_Y);
    int*    rowptr = (int*)(ws + OFF_ROWPTR);
    int*    fillc  = (int*)(ws + OFF_FILLC);
    int*    packed = (int*)(ws + OFF_PACKED);
    int*    bsum   = (int*)(ws + OFF_BSUM);
    int*    boff   = (int*)(ws + OFF_BOFF);

    hipMemsetAsync(ws + OFF_DEGI, 0, 202048, stream);
    hipMemsetAsync(ws + OFF_A + N_ENT * 512, 0, (MROWS - N_ENT) * 512, stream);

    k_deg  <<<(N_EDGE + 255) / 256, 256, 0, stream>>>(ei, degi);
    k_wprep<<<691, 256, 0, stream>>>(Wm, Wsf, W1, W2, rel, Wt1, W1t, W2t, relb);
    k_cvt  <<<3125, 256, 0, stream>>>(x, A);
    k_bsum <<<SCAN_BLKS, 256, 0, stream>>>(degi, bsum);
    k_boff <<<1, 256, 0, stream>>>(bsum, boff, rowptr);
    k_scan2<<<SCAN_BLKS, 256, 0, stream>>>(degi, boff, rowptr, fillc);
    k_fill <<<(N_EDGE + 255) / 256, 256, 0, stream>>>(ei, et, fillc, packed);
    k_agg  <<<N_ENT / 4, 256, 0, stream>>>(rowptr, packed, A, relb);
    k_hy   <<<MROWS / 64, 256, 0, stream>>>(A, Wt1, W1t, bm, b1, y, colsum, colsq);
    k_stats<<<1, 256, 0, stream>>>(colsum, colsq, gamma, beta, scale, shift);
    k_zout <<<MROWS / 64, 256, 0, stream>>>(y, scale, shift, W2t, b2, out);
}